// Round 3
// baseline (609.498 us; speedup 1.0000x reference)
//
#include <hip/hip_runtime.h>
#include <stdint.h>

typedef unsigned short ushort;
typedef __bf16 bf16x8 __attribute__((ext_vector_type(8)));
typedef float f32x4 __attribute__((ext_vector_type(4)));
typedef ushort ushort8 __attribute__((ext_vector_type(8)));

__device__ __forceinline__ float bf2f(ushort u) {
  union { unsigned int i; float f; } v; v.i = ((unsigned int)u) << 16; return v.f;
}
__device__ __forceinline__ ushort f2bf(float f) {
  union { float f; unsigned int i; } v; v.f = f;
  unsigned int r = v.i + 0x7fffu + ((v.i >> 16) & 1u);
  return (ushort)(r >> 16);
}
__device__ __forceinline__ void glds16(const ushort* g, ushort* l) {
  __builtin_amdgcn_global_load_lds(
      (const __attribute__((address_space(1))) void*)g,
      (__attribute__((address_space(3))) void*)l, 16, 0, 0);
}

// ---------------- pack: Bt[896][2304] bf16 + bias896 ----------------
__global__ __launch_bounds__(256) void pack_kernel(
    const float* __restrict__ w_kern, const float* __restrict__ b_kern,
    const float* __restrict__ w_badp, const float* __restrict__ b_badp,
    ushort* __restrict__ Bt, float* __restrict__ bias896) {
  int idx = blockIdx.x * 256 + threadIdx.x;
  const int total = 896 * 2304;
  if (idx < total) {
    int o = idx / 2304, k = idx - o * 2304;
    int c = k & 255, pos = k >> 8;
    float v = (o < 864) ? w_kern[(o * 256 + c) * 9 + pos]
                        : w_badp[((o - 864) * 256 + c) * 9 + pos];
    Bt[idx] = f2bf(v);
  } else if (idx < total + 896) {
    int o = idx - total;
    bias896[o] = (o < 864) ? b_kern[o] : b_badp[o - 864];
  }
}

// ---------------- pack2: conv weights -> [tap][oc][ic] bf16 ----------------
__global__ __launch_bounds__(256) void pack2_kernel(
    const float* __restrict__ w1, const float* __restrict__ w2,
    const float* __restrict__ w3, ushort* __restrict__ wp1,
    ushort* __restrict__ wp2, ushort* __restrict__ wp3) {
  int idx = blockIdx.x * 256 + threadIdx.x;
  if (idx < 102400) {                       // wp1 [25][128][32]
    int t = idx >> 12, rm = idx & 4095, o = rm >> 5, c = rm & 31;
    wp1[idx] = f2bf(w1[(o * 32 + c) * 25 + t]);
  } else if (idx < 102400 + 36864) {        // wp2 [9][32][128]
    int j = idx - 102400;
    int t = j >> 12, rm = j & 4095, o = rm >> 7, c = rm & 127;
    wp2[j] = f2bf(w2[(o * 128 + c) * 9 + t]);
  } else if (idx < 102400 + 36864 + 13824) {// wp3 [9][48][32]
    int j = idx - 139264;
    int t = j / 1536, rm = j - t * 1536, o = rm >> 5, c = rm & 31;
    wp3[j] = f2bf(w3[(o * 32 + c) * 9 + t]);
  }
}

// ---------------- feat: per-patch 3x3 VALID conv, 256 ch, relu, bf16 ----------------
__global__ __launch_bounds__(256) void feat_kernel(
    const float* __restrict__ x, const float* __restrict__ w_feat,
    const float* __restrict__ b_feat, ushort* __restrict__ feat) {
  __shared__ float xp[4][3][5][5];
  const int t = threadIdx.x;
  const int n0 = blockIdx.x * 4;
  for (int e = t; e < 300; e += 256) {
    int p = e / 75, rem = e - p * 75;
    int ci = rem / 25, r = rem - ci * 25, i = r / 5, j = r - i * 5;
    int n = n0 + p;
    int b = n / 9216, ph = (n >> 7) % 72, pw = n & 127;
    xp[p][ci][i][j] = x[((b * 3 + ci) * 360 + ph * 5 + i) * 640 + pw * 5 + j];
  }
  float wf[27];
#pragma unroll
  for (int m = 0; m < 27; ++m) wf[m] = w_feat[t * 27 + m];
  const float bv = b_feat[t];
  __syncthreads();
  for (int p = 0; p < 4; ++p) {
    ushort* dst = feat + (size_t)(n0 + p) * 2304 + t;
#pragma unroll
    for (int pi = 0; pi < 3; ++pi)
#pragma unroll
      for (int pj = 0; pj < 3; ++pj) {
        float acc = bv;
#pragma unroll
        for (int ci = 0; ci < 3; ++ci)
#pragma unroll
          for (int ki = 0; ki < 3; ++ki)
#pragma unroll
            for (int kj = 0; kj < 3; ++kj)
              acc = fmaf(xp[p][ci][pi + ki][pj + kj], wf[ci * 9 + ki * 3 + kj], acc);
        dst[(pi * 3 + pj) * 256] = f2bf(fmaxf(acc, 0.f));
      }
  }
}

// ---------------- kern+badp GEMM: MFMA bf16, 128x128 tile, BK=32, global_load_lds ----------------
__global__ __launch_bounds__(256) void gemm_kernel(
    const ushort* __restrict__ A, const ushort* __restrict__ Bt,
    const float* __restrict__ bias, ushort* __restrict__ C) {
  const int K = 2304, N = 896;
  __shared__ __align__(16) ushort lA[128 * 32];
  __shared__ __align__(16) ushort lB[128 * 32];
  const int m0 = blockIdx.x * 128, n0 = blockIdx.y * 128;
  const int t = threadIdx.x;
  const int lane = t & 63, wave = t >> 6;
  const int wm = wave >> 1, wn = wave & 1;
  f32x4 acc[4][4] = {};
  const ushort* gA = A + (size_t)(m0 + (t >> 2)) * K + (t & 3) * 8;
  const ushort* gB = Bt + (size_t)(n0 + (t >> 2)) * K + (t & 3) * 8;
  // wave-uniform LDS dests (lane l lands at base + l*16B, matching lA[row*32+k])
  ushort* dA0 = &lA[wave * 512];
  ushort* dA1 = &lA[2048 + wave * 512];
  ushort* dB0 = &lB[wave * 512];
  ushort* dB1 = &lB[2048 + wave * 512];
  const int aoff = (wm * 64 + (lane & 15)) * 32 + (lane >> 4) * 8;
  const int boff = (wn * 64 + (lane & 15)) * 32 + (lane >> 4) * 8;
  for (int kt = 0; kt < K; kt += 32) {
    __syncthreads();
    glds16(gA + kt, dA0);
    glds16(gA + 64 * K + kt, dA1);
    glds16(gB + kt, dB0);
    glds16(gB + 64 * K + kt, dB1);
    __syncthreads();
    bf16x8 af[4], bfr[4];
#pragma unroll
    for (int mi = 0; mi < 4; ++mi) {
      ushort8 tmp = *(const ushort8*)(&lA[aoff + mi * 512]);
      af[mi] = __builtin_bit_cast(bf16x8, tmp);
    }
#pragma unroll
    for (int ni = 0; ni < 4; ++ni) {
      ushort8 tmp = *(const ushort8*)(&lB[boff + ni * 512]);
      bfr[ni] = __builtin_bit_cast(bf16x8, tmp);
    }
#pragma unroll
    for (int mi = 0; mi < 4; ++mi)
#pragma unroll
      for (int ni = 0; ni < 4; ++ni)
        acc[mi][ni] = __builtin_amdgcn_mfma_f32_16x16x32_bf16(af[mi], bfr[ni], acc[mi][ni], 0, 0, 0);
  }
#pragma unroll
  for (int ni = 0; ni < 4; ++ni) {
    int col = n0 + wn * 64 + ni * 16 + (lane & 15);
    float bv = bias[col];
#pragma unroll
    for (int mi = 0; mi < 4; ++mi) {
      int row0 = m0 + wm * 64 + mi * 16 + (lane >> 4) * 4;
#pragma unroll
      for (int r = 0; r < 4; ++r)
        C[(size_t)(row0 + r) * N + col] = f2bf(acc[mi][ni][r] + bv);
    }
  }
}

// ---------------- apply: einsum + bias, relu, batch_to_space -> sp NHWC ----------------
__global__ __launch_bounds__(256) void apply_kernel(
    const float* __restrict__ x, const ushort* __restrict__ kernbias,
    ushort* __restrict__ sp) {
  __shared__ float xp[8][3][7][7];
  __shared__ ushort outl[8][32][25];
  const int t = threadIdx.x;
  const int n0 = blockIdx.x * 8;
  const int b = n0 / 9216, ph = (n0 >> 7) % 72, pw0 = n0 & 127;
  for (int e = t; e < 8 * 3 * 49; e += 256) ((float*)xp)[e] = 0.f;
  __syncthreads();
  for (int e = t; e < 600; e += 256) {
    int p = e / 75, rem = e - p * 75;
    int ci = rem / 25, r = rem - ci * 25, i = r / 5, j = r - i * 5;
    xp[p][ci][i + 1][j + 1] = x[((b * 3 + ci) * 360 + ph * 5 + i) * 640 + (pw0 + p) * 5 + j];
  }
  __syncthreads();
  const int p = t >> 5, f = t & 31;
  const int n = n0 + p;
  float kk[27];
#pragma unroll
  for (int k = 0; k < 27; ++k) kk[k] = bf2f(kernbias[(size_t)n * 896 + f * 27 + k]);
  const float bv = bf2f(kernbias[(size_t)n * 896 + 864 + f]);
  for (int l = 0; l < 25; ++l) {
    int li = l / 5, lj = l - li * 5;
    float s = bv;
#pragma unroll
    for (int k = 0; k < 27; ++k) {
      int ci = k / 9, rm = k - ci * 9, ki = rm / 3, kj = rm - ki * 3;
      s = fmaf(xp[p][ci][li + ki][lj + kj], kk[k], s);
    }
    outl[p][f][l] = f2bf(fmaxf(s, 0.f));
  }
  __syncthreads();
  for (int e = t; e < 6400; e += 256) {
    int f2 = e & 31;
    int idx = e >> 5;
    int i = idx / 40, c40 = idx - i * 40;
    int pp = c40 / 5, j = c40 - pp * 5;
    sp[(((size_t)b * 360 + ph * 5 + i) * 640 + pw0 * 5 + c40) * 32 + f2] = outl[pp][f2][i * 5 + j];
  }
}

// ---------------- conv1: 5x5, 32->128, MFMA implicit GEMM, NHWC, LDS-staged ----------------
__global__ __launch_bounds__(256) void conv1_kernel(
    const ushort* __restrict__ sp, const ushort* __restrict__ wp1,
    const float* __restrict__ b1, ushort* __restrict__ h1) {
  __shared__ ushort8 lin[6 * 4 * 69];
  const int t = threadIdx.x;
  const int lane = t & 63, wave = t >> 6;
  const int wh = wave >> 1, wn = wave & 1;
  const int w0 = blockIdx.x * 64, h0 = blockIdx.y * 2, b = blockIdx.z;
  for (int u = t; u < 6 * 4 * 68; u += 256) {
    int c8 = u & 3, rest = u >> 2;
    int wx = rest % 68, r = rest / 68;
    int gh = h0 - 2 + r, gw = w0 - 2 + wx;
    ushort8 v = {};
    if (gh >= 0 && gh < 360 && gw >= 0 && gw < 640)
      v = *(const ushort8*)(sp + (((size_t)b * 360 + gh) * 640 + gw) * 32 + c8 * 8);
    lin[(r * 4 + c8) * 69 + wx] = v;
  }
  __syncthreads();
  f32x4 acc[4][4] = {};
  const int abase = (lane >> 4) * 69 + (lane & 15);
  const ushort* wbase = wp1 + (wn * 64 + (lane & 15)) * 32 + (lane >> 4) * 8;
#pragma unroll 1
  for (int ki = 0; ki < 5; ++ki) {
#pragma unroll
    for (int kj = 0; kj < 5; ++kj) {
      const int tap = ki * 5 + kj;
      bf16x8 bfr[4];
#pragma unroll
      for (int nf = 0; nf < 4; ++nf) {
        ushort8 tmp = *(const ushort8*)(wbase + (size_t)tap * 4096 + nf * 512);
        bfr[nf] = __builtin_bit_cast(bf16x8, tmp);
      }
      bf16x8 afr[4];
#pragma unroll
      for (int mf = 0; mf < 4; ++mf)
        afr[mf] = __builtin_bit_cast(bf16x8, lin[(wh + ki) * 276 + abase + mf * 16 + kj]);
#pragma unroll
      for (int mf = 0; mf < 4; ++mf)
#pragma unroll
        for (int nf = 0; nf < 4; ++nf)
          acc[mf][nf] = __builtin_amdgcn_mfma_f32_16x16x32_bf16(afr[mf], bfr[nf], acc[mf][nf], 0, 0, 0);
    }
  }
  const int h = h0 + wh;
#pragma unroll
  for (int nf = 0; nf < 4; ++nf) {
    int oc = wn * 64 + nf * 16 + (lane & 15);
    float bv = b1[oc];
#pragma unroll
    for (int mf = 0; mf < 4; ++mf) {
      int w = w0 + mf * 16 + ((lane >> 4) << 2);
      size_t base = (((size_t)b * 360 + h) * 640 + w) * 128 + oc;
#pragma unroll
      for (int r = 0; r < 4; ++r)
        h1[base + (size_t)r * 128] = f2bf(fmaxf(acc[mf][nf][r] + bv, 0.f));
    }
  }
}

// ---------------- conv2: 3x3, 128->32, global-direct implicit GEMM (no LDS) ----------------
// 4 waves/block, each wave: 1h x 64w x 32oc
__global__ __launch_bounds__(256) void conv2_kernel(
    const ushort* __restrict__ h1, const ushort* __restrict__ wp2,
    const float* __restrict__ b2, ushort* __restrict__ h2) {
  const int t = threadIdx.x;
  const int lane = t & 63, wave = t >> 6;
  const int lp = lane & 15, lk = lane >> 4;
  const int w0 = blockIdx.x * 64;
  const int h = blockIdx.y * 4 + wave;
  const int b = blockIdx.z;
  f32x4 acc[4][2] = {};
  const ushort* wbase = wp2 + lp * 128 + lk * 8;
  const int gwb = w0 - 1 + lp;
#pragma unroll
  for (int ki = 0; ki < 3; ++ki) {
    const int gh = h - 1 + ki;
    const bool rok = (unsigned)gh < 360u;
    const ushort* arow = h1 + ((size_t)b * 360 + (rok ? gh : 0)) * 640 * 128 + lk * 8;
#pragma unroll
    for (int kj = 0; kj < 3; ++kj) {
      const int tap = ki * 3 + kj;
#pragma unroll
      for (int cb = 0; cb < 4; ++cb) {
        bf16x8 bfr[2];
#pragma unroll
        for (int nf = 0; nf < 2; ++nf) {
          ushort8 tmp = *(const ushort8*)(wbase + (size_t)tap * 4096 + nf * 2048 + cb * 32);
          bfr[nf] = __builtin_bit_cast(bf16x8, tmp);
        }
        bf16x8 afr[4];
#pragma unroll
        for (int mf = 0; mf < 4; ++mf) {
          int gw = gwb + mf * 16 + kj;
          ushort8 v = {};
          if (rok && (unsigned)gw < 640u)
            v = *(const ushort8*)(arow + (size_t)gw * 128 + cb * 32);
          afr[mf] = __builtin_bit_cast(bf16x8, v);
        }
#pragma unroll
        for (int mf = 0; mf < 4; ++mf)
#pragma unroll
          for (int nf = 0; nf < 2; ++nf)
            acc[mf][nf] = __builtin_amdgcn_mfma_f32_16x16x32_bf16(afr[mf], bfr[nf], acc[mf][nf], 0, 0, 0);
      }
    }
  }
#pragma unroll
  for (int nf = 0; nf < 2; ++nf) {
    int oc = nf * 16 + lp;
    float bv = b2[oc];
#pragma unroll
    for (int mf = 0; mf < 4; ++mf) {
      int w = w0 + mf * 16 + lk * 4;
      size_t base = (((size_t)b * 360 + h) * 640 + w) * 32 + oc;
#pragma unroll
      for (int r = 0; r < 4; ++r)
        h2[base + (size_t)r * 32] = f2bf(fmaxf(acc[mf][nf][r] + bv, 0.f));
    }
  }
}

// ---------------- conv3: 3x3, 32->48, MFMA, fp32 out + fused pixel_shuffle ----------------
__global__ __launch_bounds__(256) void conv3_kernel(
    const ushort* __restrict__ h2, const ushort* __restrict__ wp3,
    const float* __restrict__ b3, float* __restrict__ out) {
  __shared__ ushort8 lin[4 * 4 * 67];
  const int t = threadIdx.x;
  const int lane = t & 63, wave = t >> 6;
  const int wh = wave & 1, wm = wave >> 1;
  const int w0 = blockIdx.x * 64, h0 = blockIdx.y * 2, b = blockIdx.z;
  for (int u = t; u < 4 * 4 * 66; u += 256) {
    int c8 = u & 3, rest = u >> 2;
    int wx = rest % 66, r = rest / 66;
    int gh = h0 - 1 + r, gw = w0 - 1 + wx;
    ushort8 v = {};
    if (gh >= 0 && gh < 360 && gw >= 0 && gw < 640)
      v = *(const ushort8*)(h2 + (((size_t)b * 360 + gh) * 640 + gw) * 32 + c8 * 8);
    lin[(r * 4 + c8) * 67 + wx] = v;
  }
  __syncthreads();
  f32x4 acc[2][3] = {};
  const int abase = (lane >> 4) * 67 + wm * 32 + (lane & 15);
  const ushort* wbase = wp3 + ((lane & 15)) * 32 + (lane >> 4) * 8;
#pragma unroll 1
  for (int ki = 0; ki < 3; ++ki) {
#pragma unroll
    for (int kj = 0; kj < 3; ++kj) {
      const int tap = ki * 3 + kj;
      bf16x8 bfr[3];
#pragma unroll
      for (int nf = 0; nf < 3; ++nf) {
        ushort8 tmp = *(const ushort8*)(wbase + (size_t)tap * 1536 + nf * 512);
        bfr[nf] = __builtin_bit_cast(bf16x8, tmp);
      }
      bf16x8 afr[2];
#pragma unroll
      for (int mf = 0; mf < 2; ++mf)
        afr[mf] = __builtin_bit_cast(bf16x8, lin[(wh + ki) * 268 + abase + mf * 16 + kj]);
#pragma unroll
      for (int mf = 0; mf < 2; ++mf)
#pragma unroll
        for (int nf = 0; nf < 3; ++nf)
          acc[mf][nf] = __builtin_amdgcn_mfma_f32_16x16x32_bf16(afr[mf], bfr[nf], acc[mf][nf], 0, 0, 0);
    }
  }
  const int h = h0 + wh;
#pragma unroll
  for (int nf = 0; nf < 3; ++nf) {
    int oc = nf * 16 + (lane & 15);
    float bv = b3[oc];
    int c = oc >> 4, r1 = (oc >> 2) & 3, r2 = oc & 3;
#pragma unroll
    for (int mf = 0; mf < 2; ++mf) {
      int wb = w0 + wm * 32 + mf * 16 + ((lane >> 4) << 2);
#pragma unroll
      for (int r = 0; r < 4; ++r) {
        int w = wb + r;
        out[(((size_t)b * 3 + c) * 1440 + h * 4 + r1) * 2560 + (size_t)w * 4 + r2] =
            acc[mf][nf][r] + bv;
      }
    }
  }
}

extern "C" void kernel_launch(void* const* d_in, const int* in_sizes, int n_in,
                              void* d_out, int out_size, void* d_ws, size_t ws_size,
                              hipStream_t stream) {
  const float* x      = (const float*)d_in[0];
  const float* w_feat = (const float*)d_in[1];
  const float* b_feat = (const float*)d_in[2];
  const float* w_kern = (const float*)d_in[3];
  const float* b_kern = (const float*)d_in[4];
  const float* w_badp = (const float*)d_in[5];
  const float* b_badp = (const float*)d_in[6];
  const float* w1 = (const float*)d_in[7];
  const float* b1 = (const float*)d_in[8];
  const float* w2 = (const float*)d_in[9];
  const float* b2 = (const float*)d_in[10];
  const float* w3 = (const float*)d_in[11];
  const float* b3 = (const float*)d_in[12];

  char* ws = (char*)d_ws;
  ushort* feat     = (ushort*)(ws);
  ushort* h1       = (ushort*)(ws);
  ushort* kernbias = (ushort*)(ws + 117964800);
  ushort* h2       = (ushort*)(ws + 117964800);
  ushort* wp1      = (ushort*)(ws + 147456000);
  ushort* wp2      = (ushort*)(ws + 147660800);
  ushort* wp3      = (ushort*)(ws + 147734528);
  ushort* sp       = (ushort*)(ws + 150994944);
  ushort* Bt       = (ushort*)(ws + 180486144);
  float*  bias896  = (float*)(ws + 184614912);

  pack_kernel<<<(896 * 2304 + 896 + 255) / 256, 256, 0, stream>>>(
      w_kern, b_kern, w_badp, b_badp, Bt, bias896);
  feat_kernel<<<4608, 256, 0, stream>>>(x, w_feat, b_feat, feat);
  gemm_kernel<<<dim3(144, 7), 256, 0, stream>>>(feat, Bt, bias896, kernbias);
  apply_kernel<<<2304, 256, 0, stream>>>(x, kernbias, sp);
  pack2_kernel<<<598, 256, 0, stream>>>(w1, w2, w3, wp1, wp2, wp3);
  conv1_kernel<<<dim3(10, 180, 2), 256, 0, stream>>>(sp, wp1, b1, h1);
  conv2_kernel<<<dim3(10, 90, 2), 256, 0, stream>>>(h1, wp2, b2, h2);
  conv3_kernel<<<dim3(10, 180, 2), 256, 0, stream>>>(h2, wp3, b3, (float*)d_out);
}

// Round 4
// 514.558 us; speedup vs baseline: 1.1845x; 1.1845x over previous
//
#include <hip/hip_runtime.h>
#include <stdint.h>

typedef unsigned short ushort;
typedef __bf16 bf16x8 __attribute__((ext_vector_type(8)));
typedef float f32x4 __attribute__((ext_vector_type(4)));
typedef ushort ushort8 __attribute__((ext_vector_type(8)));

__device__ __forceinline__ float bf2f(ushort u) {
  union { unsigned int i; float f; } v; v.i = ((unsigned int)u) << 16; return v.f;
}
__device__ __forceinline__ ushort f2bf(float f) {
  union { float f; unsigned int i; } v; v.f = f;
  unsigned int r = v.i + 0x7fffu + ((v.i >> 16) & 1u);
  return (ushort)(r >> 16);
}
__device__ __forceinline__ void glds16(const ushort* g, ushort* l) {
  __builtin_amdgcn_global_load_lds(
      (const __attribute__((address_space(1))) void*)g,
      (__attribute__((address_space(3))) void*)l, 16, 0, 0);
}

// ---------------- pack: Bt[896][2304] bf16 + bias896 ----------------
__global__ __launch_bounds__(256) void pack_kernel(
    const float* __restrict__ w_kern, const float* __restrict__ b_kern,
    const float* __restrict__ w_badp, const float* __restrict__ b_badp,
    ushort* __restrict__ Bt, float* __restrict__ bias896) {
  int idx = blockIdx.x * 256 + threadIdx.x;
  const int total = 896 * 2304;
  if (idx < total) {
    int o = idx / 2304, k = idx - o * 2304;
    int c = k & 255, pos = k >> 8;
    float v = (o < 864) ? w_kern[(o * 256 + c) * 9 + pos]
                        : w_badp[((o - 864) * 256 + c) * 9 + pos];
    Bt[idx] = f2bf(v);
  } else if (idx < total + 896) {
    int o = idx - total;
    bias896[o] = (o < 864) ? b_kern[o] : b_badp[o - 864];
  }
}

// ---------------- pack2: conv weights -> [tap][oc][ic] bf16 ----------------
__global__ __launch_bounds__(256) void pack2_kernel(
    const float* __restrict__ w1, const float* __restrict__ w2,
    const float* __restrict__ w3, ushort* __restrict__ wp1,
    ushort* __restrict__ wp2, ushort* __restrict__ wp3) {
  int idx = blockIdx.x * 256 + threadIdx.x;
  if (idx < 102400) {                       // wp1 [25][128][32]
    int t = idx >> 12, rm = idx & 4095, o = rm >> 5, c = rm & 31;
    wp1[idx] = f2bf(w1[(o * 32 + c) * 25 + t]);
  } else if (idx < 102400 + 36864) {        // wp2 [9][32][128]
    int j = idx - 102400;
    int t = j >> 12, rm = j & 4095, o = rm >> 7, c = rm & 127;
    wp2[j] = f2bf(w2[(o * 128 + c) * 9 + t]);
  } else if (idx < 102400 + 36864 + 13824) {// wp3 [9][48][32]
    int j = idx - 139264;
    int t = j / 1536, rm = j - t * 1536, o = rm >> 5, c = rm & 31;
    wp3[j] = f2bf(w3[(o * 32 + c) * 9 + t]);
  }
}

// ---------------- feat: per-patch 3x3 VALID conv, 256 ch, relu, bf16 ----------------
__global__ __launch_bounds__(256) void feat_kernel(
    const float* __restrict__ x, const float* __restrict__ w_feat,
    const float* __restrict__ b_feat, ushort* __restrict__ feat) {
  __shared__ float xp[4][3][5][5];
  const int t = threadIdx.x;
  const int n0 = blockIdx.x * 4;
  for (int e = t; e < 300; e += 256) {
    int p = e / 75, rem = e - p * 75;
    int ci = rem / 25, r = rem - ci * 25, i = r / 5, j = r - i * 5;
    int n = n0 + p;
    int b = n / 9216, ph = (n >> 7) % 72, pw = n & 127;
    xp[p][ci][i][j] = x[((b * 3 + ci) * 360 + ph * 5 + i) * 640 + pw * 5 + j];
  }
  float wf[27];
#pragma unroll
  for (int m = 0; m < 27; ++m) wf[m] = w_feat[t * 27 + m];
  const float bv = b_feat[t];
  __syncthreads();
  for (int p = 0; p < 4; ++p) {
    ushort* dst = feat + (size_t)(n0 + p) * 2304 + t;
#pragma unroll
    for (int pi = 0; pi < 3; ++pi)
#pragma unroll
      for (int pj = 0; pj < 3; ++pj) {
        float acc = bv;
#pragma unroll
        for (int ci = 0; ci < 3; ++ci)
#pragma unroll
          for (int ki = 0; ki < 3; ++ki)
#pragma unroll
            for (int kj = 0; kj < 3; ++kj)
              acc = fmaf(xp[p][ci][pi + ki][pj + kj], wf[ci * 9 + ki * 3 + kj], acc);
        dst[(pi * 3 + pj) * 256] = f2bf(fmaxf(acc, 0.f));
      }
  }
}

// ---------------- kern+badp GEMM: MFMA bf16, 128x128 tile, BK=32, global_load_lds ----------------
__global__ __launch_bounds__(256) void gemm_kernel(
    const ushort* __restrict__ A, const ushort* __restrict__ Bt,
    const float* __restrict__ bias, ushort* __restrict__ C) {
  const int K = 2304, N = 896;
  __shared__ __align__(16) ushort lA[128 * 32];
  __shared__ __align__(16) ushort lB[128 * 32];
  const int m0 = blockIdx.x * 128, n0 = blockIdx.y * 128;
  const int t = threadIdx.x;
  const int lane = t & 63, wave = t >> 6;
  const int wm = wave >> 1, wn = wave & 1;
  f32x4 acc[4][4] = {};
  const ushort* gA = A + (size_t)(m0 + (t >> 2)) * K + (t & 3) * 8;
  const ushort* gB = Bt + (size_t)(n0 + (t >> 2)) * K + (t & 3) * 8;
  ushort* dA0 = &lA[wave * 512];
  ushort* dA1 = &lA[2048 + wave * 512];
  ushort* dB0 = &lB[wave * 512];
  ushort* dB1 = &lB[2048 + wave * 512];
  const int aoff = (wm * 64 + (lane & 15)) * 32 + (lane >> 4) * 8;
  const int boff = (wn * 64 + (lane & 15)) * 32 + (lane >> 4) * 8;
  for (int kt = 0; kt < K; kt += 32) {
    __syncthreads();
    glds16(gA + kt, dA0);
    glds16(gA + 64 * K + kt, dA1);
    glds16(gB + kt, dB0);
    glds16(gB + 64 * K + kt, dB1);
    __syncthreads();
    bf16x8 af[4], bfr[4];
#pragma unroll
    for (int mi = 0; mi < 4; ++mi) {
      ushort8 tmp = *(const ushort8*)(&lA[aoff + mi * 512]);
      af[mi] = __builtin_bit_cast(bf16x8, tmp);
    }
#pragma unroll
    for (int ni = 0; ni < 4; ++ni) {
      ushort8 tmp = *(const ushort8*)(&lB[boff + ni * 512]);
      bfr[ni] = __builtin_bit_cast(bf16x8, tmp);
    }
#pragma unroll
    for (int mi = 0; mi < 4; ++mi)
#pragma unroll
      for (int ni = 0; ni < 4; ++ni)
        acc[mi][ni] = __builtin_amdgcn_mfma_f32_16x16x32_bf16(af[mi], bfr[ni], acc[mi][ni], 0, 0, 0);
  }
#pragma unroll
  for (int ni = 0; ni < 4; ++ni) {
    int col = n0 + wn * 64 + ni * 16 + (lane & 15);
    float bv = bias[col];
#pragma unroll
    for (int mi = 0; mi < 4; ++mi) {
      int row0 = m0 + wm * 64 + mi * 16 + (lane >> 4) * 4;
#pragma unroll
      for (int r = 0; r < 4; ++r)
        C[(size_t)(row0 + r) * N + col] = f2bf(acc[mi][ni][r] + bv);
    }
  }
}

// ---------------- apply: einsum + bias, relu, batch_to_space -> sp NHWC ----------------
__global__ __launch_bounds__(256) void apply_kernel(
    const float* __restrict__ x, const ushort* __restrict__ kernbias,
    ushort* __restrict__ sp) {
  __shared__ float xp[8][3][7][7];
  __shared__ ushort outl[8][32][25];
  const int t = threadIdx.x;
  const int n0 = blockIdx.x * 8;
  const int b = n0 / 9216, ph = (n0 >> 7) % 72, pw0 = n0 & 127;
  for (int e = t; e < 8 * 3 * 49; e += 256) ((float*)xp)[e] = 0.f;
  __syncthreads();
  for (int e = t; e < 600; e += 256) {
    int p = e / 75, rem = e - p * 75;
    int ci = rem / 25, r = rem - ci * 25, i = r / 5, j = r - i * 5;
    xp[p][ci][i + 1][j + 1] = x[((b * 3 + ci) * 360 + ph * 5 + i) * 640 + (pw0 + p) * 5 + j];
  }
  __syncthreads();
  const int p = t >> 5, f = t & 31;
  const int n = n0 + p;
  float kk[27];
#pragma unroll
  for (int k = 0; k < 27; ++k) kk[k] = bf2f(kernbias[(size_t)n * 896 + f * 27 + k]);
  const float bv = bf2f(kernbias[(size_t)n * 896 + 864 + f]);
  for (int l = 0; l < 25; ++l) {
    int li = l / 5, lj = l - li * 5;
    float s = bv;
#pragma unroll
    for (int k = 0; k < 27; ++k) {
      int ci = k / 9, rm = k - ci * 9, ki = rm / 3, kj = rm - ki * 3;
      s = fmaf(xp[p][ci][li + ki][lj + kj], kk[k], s);
    }
    outl[p][f][l] = f2bf(fmaxf(s, 0.f));
  }
  __syncthreads();
  for (int e = t; e < 6400; e += 256) {
    int f2 = e & 31;
    int idx = e >> 5;
    int i = idx / 40, c40 = idx - i * 40;
    int pp = c40 / 5, j = c40 - pp * 5;
    sp[(((size_t)b * 360 + ph * 5 + i) * 640 + pw0 * 5 + c40) * 32 + f2] = outl[pp][f2][i * 5 + j];
  }
}

// ---------------- conv1: 5x5, 32->128, MFMA implicit GEMM, NHWC, 4h tile ----------------
// 512 threads = 8 waves: (wh in [0,4), wn in [0,2)); per wave 1h x 64w x 64oc
__global__ __launch_bounds__(512) void conv1_kernel(
    const ushort* __restrict__ sp, const ushort* __restrict__ wp1,
    const float* __restrict__ b1, ushort* __restrict__ h1) {
  __shared__ ushort8 lin[8 * 4 * 69];   // [(r*4+c8)*69 + wx], r<8, wx<68
  const int t = threadIdx.x;
  const int lane = t & 63, wave = t >> 6;
  const int wh = wave >> 1, wn = wave & 1;
  const int w0 = blockIdx.x * 64, h0 = blockIdx.y * 4, b = blockIdx.z;
  for (int u = t; u < 8 * 4 * 68; u += 512) {
    int c8 = u & 3, rest = u >> 2;
    int wx = rest % 68, r = rest / 68;
    int gh = h0 - 2 + r, gw = w0 - 2 + wx;
    ushort8 v = {};
    if ((unsigned)gh < 360u && (unsigned)gw < 640u)
      v = *(const ushort8*)(sp + (((size_t)b * 360 + gh) * 640 + gw) * 32 + c8 * 8);
    lin[(r * 4 + c8) * 69 + wx] = v;
  }
  __syncthreads();
  f32x4 acc[4][4] = {};
  const int abase = (lane >> 4) * 69 + (lane & 15);
  const ushort* wbase = wp1 + (wn * 64 + (lane & 15)) * 32 + (lane >> 4) * 8;
#pragma unroll 1
  for (int ki = 0; ki < 5; ++ki) {
#pragma unroll
    for (int kj = 0; kj < 5; ++kj) {
      const int tap = ki * 5 + kj;
      bf16x8 bfr[4];
#pragma unroll
      for (int nf = 0; nf < 4; ++nf) {
        ushort8 tmp = *(const ushort8*)(wbase + (size_t)tap * 4096 + nf * 512);
        bfr[nf] = __builtin_bit_cast(bf16x8, tmp);
      }
      bf16x8 afr[4];
#pragma unroll
      for (int mf = 0; mf < 4; ++mf)
        afr[mf] = __builtin_bit_cast(bf16x8, lin[(wh + ki) * 276 + abase + mf * 16 + kj]);
#pragma unroll
      for (int mf = 0; mf < 4; ++mf)
#pragma unroll
        for (int nf = 0; nf < 4; ++nf)
          acc[mf][nf] = __builtin_amdgcn_mfma_f32_16x16x32_bf16(afr[mf], bfr[nf], acc[mf][nf], 0, 0, 0);
    }
  }
  const int h = h0 + wh;
#pragma unroll
  for (int nf = 0; nf < 4; ++nf) {
    int oc = wn * 64 + nf * 16 + (lane & 15);
    float bv = b1[oc];
#pragma unroll
    for (int mf = 0; mf < 4; ++mf) {
      int w = w0 + mf * 16 + ((lane >> 4) << 2);
      size_t base = (((size_t)b * 360 + h) * 640 + w) * 128 + oc;
#pragma unroll
      for (int r = 0; r < 4; ++r)
        h1[base + (size_t)r * 128] = f2bf(fmaxf(acc[mf][nf][r] + bv, 0.f));
    }
  }
}

// ---------------- conv2: 3x3, 128->32, LDS double-buffered chunked pipeline ----------------
// tile 4h x 64w x 32oc; 4 waves = 4 h rows; 4 chunks of 32 input channels
__device__ __forceinline__ void c2_load(ushort8* stg, const ushort* __restrict__ h1,
                                        int t, int b, int h0, int w0, int cb) {
#pragma unroll
  for (int j = 0; j < 7; ++j) {
    int u = t + j * 256;
    ushort8 v = {};
    if (u < 1584) {
      int r = u / 264, rem = u - r * 264;
      int c8 = rem / 66, wx = rem - c8 * 66;
      int gh = h0 - 1 + r, gw = w0 - 1 + wx;
      if ((unsigned)gh < 360u && (unsigned)gw < 640u)
        v = *(const ushort8*)(h1 + (((size_t)b * 360 + gh) * 640 + gw) * 128 + cb * 32 + c8 * 8);
    }
    stg[j] = v;
  }
}
__device__ __forceinline__ void c2_write(const ushort8* stg, ushort8* buf, int t) {
#pragma unroll
  for (int j = 0; j < 7; ++j) {
    int u = t + j * 256;
    if (u < 1584) {
      int r = u / 264, rem = u - r * 264;
      int c8 = rem / 66, wx = rem - c8 * 66;
      buf[c8 * 414 + r * 69 + wx] = stg[j];
    }
  }
}
__device__ __forceinline__ void c2_compute(const ushort8* buf, const ushort* __restrict__ wp2,
                                           int cb, int wave, int lp, int lk, f32x4 acc[4][2]) {
#pragma unroll
  for (int ki = 0; ki < 3; ++ki) {
    const int rb = lk * 414 + (wave + ki) * 69;
#pragma unroll
    for (int kj = 0; kj < 3; ++kj) {
      const int tap = ki * 3 + kj;
      bf16x8 bfr[2];
#pragma unroll
      for (int nf = 0; nf < 2; ++nf) {
        ushort8 tmp = *(const ushort8*)(wp2 + tap * 4096 + nf * 2048 + lp * 128 + cb * 32 + lk * 8);
        bfr[nf] = __builtin_bit_cast(bf16x8, tmp);
      }
      bf16x8 afr[4];
#pragma unroll
      for (int mf = 0; mf < 4; ++mf)
        afr[mf] = __builtin_bit_cast(bf16x8, buf[rb + lp + mf * 16 + kj]);
#pragma unroll
      for (int mf = 0; mf < 4; ++mf)
#pragma unroll
        for (int nf = 0; nf < 2; ++nf)
          acc[mf][nf] = __builtin_amdgcn_mfma_f32_16x16x32_bf16(afr[mf], bfr[nf], acc[mf][nf], 0, 0, 0);
    }
  }
}

__global__ __launch_bounds__(256) void conv2_kernel(
    const ushort* __restrict__ h1, const ushort* __restrict__ wp2,
    const float* __restrict__ b2, ushort* __restrict__ h2) {
  __shared__ ushort8 lin[2][4 * 414];   // [buf][c8*414 + r*69 + wx]
  const int t = threadIdx.x;
  const int lane = t & 63, wave = t >> 6;
  const int lp = lane & 15, lk = lane >> 4;
  const int w0 = blockIdx.x * 64, h0 = blockIdx.y * 4, b = blockIdx.z;
  f32x4 acc[4][2] = {};
  ushort8 stg[7];
  c2_load(stg, h1, t, b, h0, w0, 0);
#pragma unroll
  for (int it = 0; it < 5; ++it) {
    __syncthreads();
    if (it < 4) c2_write(stg, lin[it & 1], t);
    if (it < 3) c2_load(stg, h1, t, b, h0, w0, it + 1);
    if (it >= 1) c2_compute(lin[(it - 1) & 1], wp2, it - 1, wave, lp, lk, acc);
  }
  const int h = h0 + wave;
#pragma unroll
  for (int nf = 0; nf < 2; ++nf) {
    int oc = nf * 16 + lp;
    float bv = b2[oc];
#pragma unroll
    for (int mf = 0; mf < 4; ++mf) {
      int w = w0 + mf * 16 + lk * 4;
      size_t base = (((size_t)b * 360 + h) * 640 + w) * 32 + oc;
#pragma unroll
      for (int r = 0; r < 4; ++r)
        h2[base + (size_t)r * 32] = f2bf(fmaxf(acc[mf][nf][r] + bv, 0.f));
    }
  }
}

// ---------------- conv3: 3x3, 32->48, MFMA, fp32 out + fused pixel_shuffle ----------------
__global__ __launch_bounds__(256) void conv3_kernel(
    const ushort* __restrict__ h2, const ushort* __restrict__ wp3,
    const float* __restrict__ b3, float* __restrict__ out) {
  __shared__ ushort8 lin[4 * 4 * 67];
  const int t = threadIdx.x;
  const int lane = t & 63, wave = t >> 6;
  const int wh = wave & 1, wm = wave >> 1;
  const int w0 = blockIdx.x * 64, h0 = blockIdx.y * 2, b = blockIdx.z;
  for (int u = t; u < 4 * 4 * 66; u += 256) {
    int c8 = u & 3, rest = u >> 2;
    int wx = rest % 66, r = rest / 66;
    int gh = h0 - 1 + r, gw = w0 - 1 + wx;
    ushort8 v = {};
    if (gh >= 0 && gh < 360 && gw >= 0 && gw < 640)
      v = *(const ushort8*)(h2 + (((size_t)b * 360 + gh) * 640 + gw) * 32 + c8 * 8);
    lin[(r * 4 + c8) * 67 + wx] = v;
  }
  __syncthreads();
  f32x4 acc[2][3] = {};
  const int abase = (lane >> 4) * 67 + wm * 32 + (lane & 15);
  const ushort* wbase = wp3 + ((lane & 15)) * 32 + (lane >> 4) * 8;
#pragma unroll 1
  for (int ki = 0; ki < 3; ++ki) {
#pragma unroll
    for (int kj = 0; kj < 3; ++kj) {
      const int tap = ki * 3 + kj;
      bf16x8 bfr[3];
#pragma unroll
      for (int nf = 0; nf < 3; ++nf) {
        ushort8 tmp = *(const ushort8*)(wbase + (size_t)tap * 1536 + nf * 512);
        bfr[nf] = __builtin_bit_cast(bf16x8, tmp);
      }
      bf16x8 afr[2];
#pragma unroll
      for (int mf = 0; mf < 2; ++mf)
        afr[mf] = __builtin_bit_cast(bf16x8, lin[(wh + ki) * 268 + abase + mf * 16 + kj]);
#pragma unroll
      for (int mf = 0; mf < 2; ++mf)
#pragma unroll
        for (int nf = 0; nf < 3; ++nf)
          acc[mf][nf] = __builtin_amdgcn_mfma_f32_16x16x32_bf16(afr[mf], bfr[nf], acc[mf][nf], 0, 0, 0);
    }
  }
  const int h = h0 + wh;
#pragma unroll
  for (int nf = 0; nf < 3; ++nf) {
    int oc = nf * 16 + (lane & 15);
    float bv = b3[oc];
    int c = oc >> 4, r1 = (oc >> 2) & 3, r2 = oc & 3;
#pragma unroll
    for (int mf = 0; mf < 2; ++mf) {
      int wb = w0 + wm * 32 + mf * 16 + ((lane >> 4) << 2);
#pragma unroll
      for (int r = 0; r < 4; ++r) {
        int w = wb + r;
        out[(((size_t)b * 3 + c) * 1440 + h * 4 + r1) * 2560 + (size_t)w * 4 + r2] =
            acc[mf][nf][r] + bv;
      }
    }
  }
}

extern "C" void kernel_launch(void* const* d_in, const int* in_sizes, int n_in,
                              void* d_out, int out_size, void* d_ws, size_t ws_size,
                              hipStream_t stream) {
  const float* x      = (const float*)d_in[0];
  const float* w_feat = (const float*)d_in[1];
  const float* b_feat = (const float*)d_in[2];
  const float* w_kern = (const float*)d_in[3];
  const float* b_kern = (const float*)d_in[4];
  const float* w_badp = (const float*)d_in[5];
  const float* b_badp = (const float*)d_in[6];
  const float* w1 = (const float*)d_in[7];
  const float* b1 = (const float*)d_in[8];
  const float* w2 = (const float*)d_in[9];
  const float* b2 = (const float*)d_in[10];
  const float* w3 = (const float*)d_in[11];
  const float* b3 = (const float*)d_in[12];

  char* ws = (char*)d_ws;
  ushort* feat     = (ushort*)(ws);
  ushort* h1       = (ushort*)(ws);
  ushort* kernbias = (ushort*)(ws + 117964800);
  ushort* h2       = (ushort*)(ws + 117964800);
  ushort* wp1      = (ushort*)(ws + 147456000);
  ushort* wp2      = (ushort*)(ws + 147660800);
  ushort* wp3      = (ushort*)(ws + 147734528);
  ushort* sp       = (ushort*)(ws + 150994944);
  ushort* Bt       = (ushort*)(ws + 180486144);
  float*  bias896  = (float*)(ws + 184614912);

  pack_kernel<<<(896 * 2304 + 896 + 255) / 256, 256, 0, stream>>>(
      w_kern, b_kern, w_badp, b_badp, Bt, bias896);
  feat_kernel<<<4608, 256, 0, stream>>>(x, w_feat, b_feat, feat);
  gemm_kernel<<<dim3(144, 7), 256, 0, stream>>>(feat, Bt, bias896, kernbias);
  apply_kernel<<<2304, 256, 0, stream>>>(x, kernbias, sp);
  pack2_kernel<<<598, 256, 0, stream>>>(w1, w2, w3, wp1, wp2, wp3);
  conv1_kernel<<<dim3(10, 90, 2), 512, 0, stream>>>(sp, wp1, b1, h1);
  conv2_kernel<<<dim3(10, 90, 2), 256, 0, stream>>>(h1, wp2, b2, h2);
  conv3_kernel<<<dim3(10, 180, 2), 256, 0, stream>>>(h2, wp3, b3, (float*)d_out);
}

// Round 5
// 512.267 us; speedup vs baseline: 1.1898x; 1.0045x over previous
//
#include <hip/hip_runtime.h>
#include <stdint.h>

typedef unsigned short ushort;
typedef __bf16 bf16x8 __attribute__((ext_vector_type(8)));
typedef float f32x4 __attribute__((ext_vector_type(4)));
typedef ushort ushort8 __attribute__((ext_vector_type(8)));
typedef ushort us4 __attribute__((ext_vector_type(4)));

__device__ __forceinline__ float bf2f(ushort u) {
  union { unsigned int i; float f; } v; v.i = ((unsigned int)u) << 16; return v.f;
}
__device__ __forceinline__ ushort f2bf(float f) {
  union { float f; unsigned int i; } v; v.f = f;
  unsigned int r = v.i + 0x7fffu + ((v.i >> 16) & 1u);
  return (ushort)(r >> 16);
}
__device__ __forceinline__ void glds16(const ushort* g, ushort* l) {
  __builtin_amdgcn_global_load_lds(
      (const __attribute__((address_space(1))) void*)g,
      (__attribute__((address_space(3))) void*)l, 16, 0, 0);
}
__device__ __forceinline__ bf16x8 ldw(const ushort* p) {
  return __builtin_bit_cast(bf16x8, *(const ushort8*)p);
}

// ---------------- pack: Bt[896][2304] bf16 + bias896 ----------------
__global__ __launch_bounds__(256) void pack_kernel(
    const float* __restrict__ w_kern, const float* __restrict__ b_kern,
    const float* __restrict__ w_badp, const float* __restrict__ b_badp,
    ushort* __restrict__ Bt, float* __restrict__ bias896) {
  int idx = blockIdx.x * 256 + threadIdx.x;
  const int total = 896 * 2304;
  if (idx < total) {
    int o = idx / 2304, k = idx - o * 2304;
    int c = k & 255, pos = k >> 8;
    float v = (o < 864) ? w_kern[(o * 256 + c) * 9 + pos]
                        : w_badp[((o - 864) * 256 + c) * 9 + pos];
    Bt[idx] = f2bf(v);
  } else if (idx < total + 896) {
    int o = idx - total;
    bias896[o] = (o < 864) ? b_kern[o] : b_badp[o - 864];
  }
}

// ---------------- pack2: conv weights -> [tap][oc][ic] bf16 ----------------
__global__ __launch_bounds__(256) void pack2_kernel(
    const float* __restrict__ w1, const float* __restrict__ w2,
    const float* __restrict__ w3, ushort* __restrict__ wp1,
    ushort* __restrict__ wp2, ushort* __restrict__ wp3) {
  int idx = blockIdx.x * 256 + threadIdx.x;
  if (idx < 102400) {                       // wp1 [25][128][32]
    int t = idx >> 12, rm = idx & 4095, o = rm >> 5, c = rm & 31;
    wp1[idx] = f2bf(w1[(o * 32 + c) * 25 + t]);
  } else if (idx < 102400 + 36864) {        // wp2 [9][32][128]
    int j = idx - 102400;
    int t = j >> 12, rm = j & 4095, o = rm >> 7, c = rm & 127;
    wp2[j] = f2bf(w2[(o * 128 + c) * 9 + t]);
  } else if (idx < 102400 + 36864 + 13824) {// wp3 [9][48][32]
    int j = idx - 139264;
    int t = j / 1536, rm = j - t * 1536, o = rm >> 5, c = rm & 31;
    wp3[j] = f2bf(w3[(o * 32 + c) * 9 + t]);
  }
}

// ---------------- feat: per-patch 3x3 VALID conv, 256 ch, relu, bf16 ----------------
__global__ __launch_bounds__(256) void feat_kernel(
    const float* __restrict__ x, const float* __restrict__ w_feat,
    const float* __restrict__ b_feat, ushort* __restrict__ feat) {
  __shared__ float xp[4][3][5][5];
  const int t = threadIdx.x;
  const int n0 = blockIdx.x * 4;
  for (int e = t; e < 300; e += 256) {
    int p = e / 75, rem = e - p * 75;
    int ci = rem / 25, r = rem - ci * 25, i = r / 5, j = r - i * 5;
    int n = n0 + p;
    int b = n / 9216, ph = (n >> 7) % 72, pw = n & 127;
    xp[p][ci][i][j] = x[((b * 3 + ci) * 360 + ph * 5 + i) * 640 + pw * 5 + j];
  }
  float wf[27];
#pragma unroll
  for (int m = 0; m < 27; ++m) wf[m] = w_feat[t * 27 + m];
  const float bv = b_feat[t];
  __syncthreads();
  for (int p = 0; p < 4; ++p) {
    ushort* dst = feat + (size_t)(n0 + p) * 2304 + t;
#pragma unroll
    for (int pi = 0; pi < 3; ++pi)
#pragma unroll
      for (int pj = 0; pj < 3; ++pj) {
        float acc = bv;
#pragma unroll
        for (int ci = 0; ci < 3; ++ci)
#pragma unroll
          for (int ki = 0; ki < 3; ++ki)
#pragma unroll
            for (int kj = 0; kj < 3; ++kj)
              acc = fmaf(xp[p][ci][pi + ki][pj + kj], wf[ci * 9 + ki * 3 + kj], acc);
        dst[(pi * 3 + pj) * 256] = f2bf(fmaxf(acc, 0.f));
      }
  }
}

// ---------------- kern+badp GEMM: MFMA bf16, 128x128 tile, BK=32, global_load_lds ----------------
__global__ __launch_bounds__(256) void gemm_kernel(
    const ushort* __restrict__ A, const ushort* __restrict__ Bt,
    const float* __restrict__ bias, ushort* __restrict__ C) {
  const int K = 2304, N = 896;
  __shared__ __align__(16) ushort lA[128 * 32];
  __shared__ __align__(16) ushort lB[128 * 32];
  const int m0 = blockIdx.x * 128, n0 = blockIdx.y * 128;
  const int t = threadIdx.x;
  const int lane = t & 63, wave = t >> 6;
  const int wm = wave >> 1, wn = wave & 1;
  f32x4 acc[4][4] = {};
  const ushort* gA = A + (size_t)(m0 + (t >> 2)) * K + (t & 3) * 8;
  const ushort* gB = Bt + (size_t)(n0 + (t >> 2)) * K + (t & 3) * 8;
  ushort* dA0 = &lA[wave * 512];
  ushort* dA1 = &lA[2048 + wave * 512];
  ushort* dB0 = &lB[wave * 512];
  ushort* dB1 = &lB[2048 + wave * 512];
  const int aoff = (wm * 64 + (lane & 15)) * 32 + (lane >> 4) * 8;
  const int boff = (wn * 64 + (lane & 15)) * 32 + (lane >> 4) * 8;
  for (int kt = 0; kt < K; kt += 32) {
    __syncthreads();
    glds16(gA + kt, dA0);
    glds16(gA + 64 * K + kt, dA1);
    glds16(gB + kt, dB0);
    glds16(gB + 64 * K + kt, dB1);
    __syncthreads();
    bf16x8 af[4], bfr[4];
#pragma unroll
    for (int mi = 0; mi < 4; ++mi) {
      ushort8 tmp = *(const ushort8*)(&lA[aoff + mi * 512]);
      af[mi] = __builtin_bit_cast(bf16x8, tmp);
    }
#pragma unroll
    for (int ni = 0; ni < 4; ++ni) {
      ushort8 tmp = *(const ushort8*)(&lB[boff + ni * 512]);
      bfr[ni] = __builtin_bit_cast(bf16x8, tmp);
    }
#pragma unroll
    for (int mi = 0; mi < 4; ++mi)
#pragma unroll
      for (int ni = 0; ni < 4; ++ni)
        acc[mi][ni] = __builtin_amdgcn_mfma_f32_16x16x32_bf16(af[mi], bfr[ni], acc[mi][ni], 0, 0, 0);
  }
#pragma unroll
  for (int ni = 0; ni < 4; ++ni) {
    int col = n0 + wn * 64 + ni * 16 + (lane & 15);
    float bv = bias[col];
#pragma unroll
    for (int mi = 0; mi < 4; ++mi) {
      int row0 = m0 + wm * 64 + mi * 16 + (lane >> 4) * 4;
#pragma unroll
      for (int r = 0; r < 4; ++r)
        C[(size_t)(row0 + r) * N + col] = f2bf(acc[mi][ni][r] + bv);
    }
  }
}

// ---------------- apply: einsum + bias, relu, batch_to_space -> sp NHWC ----------------
__global__ __launch_bounds__(256) void apply_kernel(
    const float* __restrict__ x, const ushort* __restrict__ kernbias,
    ushort* __restrict__ sp) {
  __shared__ float xp[8][3][7][7];
  __shared__ ushort outl[8][32][25];
  const int t = threadIdx.x;
  const int n0 = blockIdx.x * 8;
  const int b = n0 / 9216, ph = (n0 >> 7) % 72, pw0 = n0 & 127;
  for (int e = t; e < 8 * 3 * 49; e += 256) ((float*)xp)[e] = 0.f;
  __syncthreads();
  for (int e = t; e < 600; e += 256) {
    int p = e / 75, rem = e - p * 75;
    int ci = rem / 25, r = rem - ci * 25, i = r / 5, j = r - i * 5;
    xp[p][ci][i + 1][j + 1] = x[((b * 3 + ci) * 360 + ph * 5 + i) * 640 + (pw0 + p) * 5 + j];
  }
  __syncthreads();
  const int p = t >> 5, f = t & 31;
  const int n = n0 + p;
  float kk[27];
#pragma unroll
  for (int k = 0; k < 27; ++k) kk[k] = bf2f(kernbias[(size_t)n * 896 + f * 27 + k]);
  const float bv = bf2f(kernbias[(size_t)n * 896 + 864 + f]);
  for (int l = 0; l < 25; ++l) {
    int li = l / 5, lj = l - li * 5;
    float s = bv;
#pragma unroll
    for (int k = 0; k < 27; ++k) {
      int ci = k / 9, rm = k - ci * 9, ki = rm / 3, kj = rm - ki * 3;
      s = fmaf(xp[p][ci][li + ki][lj + kj], kk[k], s);
    }
    outl[p][f][l] = f2bf(fmaxf(s, 0.f));
  }
  __syncthreads();
  for (int e = t; e < 6400; e += 256) {
    int f2 = e & 31;
    int idx = e >> 5;
    int i = idx / 40, c40 = idx - i * 40;
    int pp = c40 / 5, j = c40 - pp * 5;
    sp[(((size_t)b * 360 + ph * 5 + i) * 640 + pw0 * 5 + c40) * 32 + f2] = outl[pp][f2][i * 5 + j];
  }
}

// ---------------- conv1: 5x5, 32->128, MFMA implicit GEMM, NHWC, 4h tile ----------------
// 512 threads = 8 waves: (wh in [0,4), wn in [0,2)); per wave 1h x 64w x 64oc.
// Swapped MFMA operands: D-row = oc (contiguous) -> packed ushort4 stores.
// Flat 25-tap pair loop with 1-tap-ahead weight prefetch (kills ki-boundary L2 bubbles).
__global__ __launch_bounds__(512) void conv1_kernel(
    const ushort* __restrict__ sp, const ushort* __restrict__ wp1,
    const float* __restrict__ b1, ushort* __restrict__ h1) {
  __shared__ ushort8 lin[8 * 4 * 69];   // [(r*4+c8)*69 + wx], r<8, wx<68
  const int t = threadIdx.x;
  const int lane = t & 63, wave = t >> 6;
  const int wh = wave >> 1, wn = wave & 1;
  const int w0 = blockIdx.x * 64, h0 = blockIdx.y * 4, b = blockIdx.z;
  for (int u = t; u < 8 * 4 * 68; u += 512) {
    int c8 = u & 3, rest = u >> 2;
    int wx = rest % 68, r = rest / 68;
    int gh = h0 - 2 + r, gw = w0 - 2 + wx;
    ushort8 v = {};
    if ((unsigned)gh < 360u && (unsigned)gw < 640u)
      v = *(const ushort8*)(sp + (((size_t)b * 360 + gh) * 640 + gw) * 32 + c8 * 8);
    lin[(r * 4 + c8) * 69 + wx] = v;
  }
  __syncthreads();
  f32x4 acc[4][4] = {};
  const int lp = lane & 15, lk = lane >> 4;
  const int abase0 = lk * 69 + lp;
  const ushort* wb = wp1 + (wn * 64 + lp) * 32 + lk * 8;

  bf16x8 wc[4], wx_[4];
#pragma unroll
  for (int nf = 0; nf < 4; ++nf) wc[nf] = ldw(wb + nf * 512);

  auto do_tap = [&](int tp, const bf16x8* wr) {
    int ki = (tp * 13) >> 6, kj = tp - ki * 5;
    int ab = (wh + ki) * 276 + abase0 + kj;
    bf16x8 afr[4];
#pragma unroll
    for (int mf = 0; mf < 4; ++mf)
      afr[mf] = __builtin_bit_cast(bf16x8, lin[ab + mf * 16]);
#pragma unroll
    for (int mf = 0; mf < 4; ++mf)
#pragma unroll
      for (int nf = 0; nf < 4; ++nf)
        acc[mf][nf] = __builtin_amdgcn_mfma_f32_16x16x32_bf16(wr[nf], afr[mf], acc[mf][nf], 0, 0, 0);
  };

#pragma unroll 1
  for (int tp = 0; tp < 24; tp += 2) {
#pragma unroll
    for (int nf = 0; nf < 4; ++nf) wx_[nf] = ldw(wb + (tp + 1) * 4096 + nf * 512);
    do_tap(tp, wc);
#pragma unroll
    for (int nf = 0; nf < 4; ++nf) wc[nf] = ldw(wb + (tp + 2) * 4096 + nf * 512);
    do_tap(tp + 1, wx_);
  }
  do_tap(24, wc);

  const int h = h0 + wh;
#pragma unroll
  for (int nf = 0; nf < 4; ++nf) {
    const int oc0 = wn * 64 + nf * 16 + lk * 4;
    f32x4 bv = *(const f32x4*)(b1 + oc0);
#pragma unroll
    for (int mf = 0; mf < 4; ++mf) {
      const int w = w0 + mf * 16 + lp;
      us4 pk;
#pragma unroll
      for (int r = 0; r < 4; ++r) pk[r] = f2bf(fmaxf(acc[mf][nf][r] + bv[r], 0.f));
      *(us4*)(&h1[(((size_t)b * 360 + h) * 640 + w) * 128 + oc0]) = pk;
    }
  }
}

// ---------------- conv2: 3x3, 128->32, LDS double-buffered chunked pipeline ----------------
// tile 4h x 64w x 32oc; 4 waves = 4 h rows; 4 chunks of 32 input channels
__device__ __forceinline__ void c2_load(ushort8* stg, const ushort* __restrict__ h1,
                                        int t, int b, int h0, int w0, int cb) {
#pragma unroll
  for (int j = 0; j < 7; ++j) {
    int u = t + j * 256;
    ushort8 v = {};
    if (u < 1584) {
      int r = u / 264, rem = u - r * 264;
      int c8 = rem / 66, wx = rem - c8 * 66;
      int gh = h0 - 1 + r, gw = w0 - 1 + wx;
      if ((unsigned)gh < 360u && (unsigned)gw < 640u)
        v = *(const ushort8*)(h1 + (((size_t)b * 360 + gh) * 640 + gw) * 128 + cb * 32 + c8 * 8);
    }
    stg[j] = v;
  }
}
__device__ __forceinline__ void c2_write(const ushort8* stg, ushort8* buf, int t) {
#pragma unroll
  for (int j = 0; j < 7; ++j) {
    int u = t + j * 256;
    if (u < 1584) {
      int r = u / 264, rem = u - r * 264;
      int c8 = rem / 66, wx = rem - c8 * 66;
      buf[c8 * 414 + r * 69 + wx] = stg[j];
    }
  }
}
__device__ __forceinline__ void c2_compute(const ushort8* buf, const ushort* __restrict__ wp2,
                                           int cb, int wave, int lp, int lk, f32x4 acc[4][2]) {
#pragma unroll
  for (int ki = 0; ki < 3; ++ki) {
    const int rb = lk * 414 + (wave + ki) * 69;
#pragma unroll
    for (int kj = 0; kj < 3; ++kj) {
      const int tap = ki * 3 + kj;
      bf16x8 bfr[2];
#pragma unroll
      for (int nf = 0; nf < 2; ++nf) {
        ushort8 tmp = *(const ushort8*)(wp2 + tap * 4096 + nf * 2048 + lp * 128 + cb * 32 + lk * 8);
        bfr[nf] = __builtin_bit_cast(bf16x8, tmp);
      }
      bf16x8 afr[4];
#pragma unroll
      for (int mf = 0; mf < 4; ++mf)
        afr[mf] = __builtin_bit_cast(bf16x8, buf[rb + lp + mf * 16 + kj]);
#pragma unroll
      for (int mf = 0; mf < 4; ++mf)
#pragma unroll
        for (int nf = 0; nf < 2; ++nf)
          acc[mf][nf] = __builtin_amdgcn_mfma_f32_16x16x32_bf16(bfr[nf], afr[mf], acc[mf][nf], 0, 0, 0);
    }
  }
}

__global__ __launch_bounds__(256) void conv2_kernel(
    const ushort* __restrict__ h1, const ushort* __restrict__ wp2,
    const float* __restrict__ b2, ushort* __restrict__ h2) {
  __shared__ ushort8 lin[2][4 * 414];   // [buf][c8*414 + r*69 + wx]
  const int t = threadIdx.x;
  const int lane = t & 63, wave = t >> 6;
  const int lp = lane & 15, lk = lane >> 4;
  const int w0 = blockIdx.x * 64, h0 = blockIdx.y * 4, b = blockIdx.z;
  f32x4 acc[4][2] = {};
  ushort8 stg[7];
  c2_load(stg, h1, t, b, h0, w0, 0);
#pragma unroll
  for (int it = 0; it < 5; ++it) {
    __syncthreads();
    if (it < 4) c2_write(stg, lin[it & 1], t);
    if (it < 3) c2_load(stg, h1, t, b, h0, w0, it + 1);
    if (it >= 1) c2_compute(lin[(it - 1) & 1], wp2, it - 1, wave, lp, lk, acc);
  }
  const int h = h0 + wave;
#pragma unroll
  for (int nf = 0; nf < 2; ++nf) {
    const int oc0 = nf * 16 + lk * 4;
    f32x4 bv = *(const f32x4*)(b2 + oc0);
#pragma unroll
    for (int mf = 0; mf < 4; ++mf) {
      const int w = w0 + mf * 16 + lp;
      us4 pk;
#pragma unroll
      for (int r = 0; r < 4; ++r) pk[r] = f2bf(fmaxf(acc[mf][nf][r] + bv[r], 0.f));
      *(us4*)(&h2[(((size_t)b * 360 + h) * 640 + w) * 32 + oc0]) = pk;
    }
  }
}

// ---------------- conv3: 3x3, 32->48, MFMA, fp32 out + fused pixel_shuffle ----------------
// Swapped operands: lane's 4 acc regs = oc quad = consecutive output-x -> float4 stores.
__global__ __launch_bounds__(256) void conv3_kernel(
    const ushort* __restrict__ h2, const ushort* __restrict__ wp3,
    const float* __restrict__ b3, float* __restrict__ out) {
  __shared__ ushort8 lin[4 * 4 * 67];
  const int t = threadIdx.x;
  const int lane = t & 63, wave = t >> 6;
  const int wh = wave & 1, wm = wave >> 1;
  const int lp = lane & 15, lk = lane >> 4;
  const int w0 = blockIdx.x * 64, h0 = blockIdx.y * 2, b = blockIdx.z;
  for (int u = t; u < 4 * 4 * 66; u += 256) {
    int c8 = u & 3, rest = u >> 2;
    int wx = rest % 66, r = rest / 66;
    int gh = h0 - 1 + r, gw = w0 - 1 + wx;
    ushort8 v = {};
    if (gh >= 0 && gh < 360 && gw >= 0 && gw < 640)
      v = *(const ushort8*)(h2 + (((size_t)b * 360 + gh) * 640 + gw) * 32 + c8 * 8);
    lin[(r * 4 + c8) * 67 + wx] = v;
  }
  __syncthreads();
  f32x4 acc[2][3] = {};
  const int abase = lk * 67 + wm * 32 + lp;
  const ushort* wbase = wp3 + lp * 32 + lk * 8;
#pragma unroll 1
  for (int ki = 0; ki < 3; ++ki) {
#pragma unroll
    for (int kj = 0; kj < 3; ++kj) {
      const int tap = ki * 3 + kj;
      bf16x8 bfr[3];
#pragma unroll
      for (int nf = 0; nf < 3; ++nf) {
        ushort8 tmp = *(const ushort8*)(wbase + (size_t)tap * 1536 + nf * 512);
        bfr[nf] = __builtin_bit_cast(bf16x8, tmp);
      }
      bf16x8 afr[2];
#pragma unroll
      for (int mf = 0; mf < 2; ++mf)
        afr[mf] = __builtin_bit_cast(bf16x8, lin[(wh + ki) * 268 + abase + mf * 16 + kj]);
#pragma unroll
      for (int mf = 0; mf < 2; ++mf)
#pragma unroll
        for (int nf = 0; nf < 3; ++nf)
          acc[mf][nf] = __builtin_amdgcn_mfma_f32_16x16x32_bf16(bfr[nf], afr[mf], acc[mf][nf], 0, 0, 0);
    }
  }
  const int h = h0 + wh;
#pragma unroll
  for (int nf = 0; nf < 3; ++nf) {
    f32x4 bv = *(const f32x4*)(b3 + nf * 16 + lk * 4);
#pragma unroll
    for (int mf = 0; mf < 2; ++mf) {
      const int w = w0 + wm * 32 + mf * 16 + lp;
      f32x4 o;
#pragma unroll
      for (int r = 0; r < 4; ++r) o[r] = acc[mf][nf][r] + bv[r];
      *(f32x4*)(&out[(((size_t)b * 3 + nf) * 1440 + h * 4 + lk) * 2560 + (size_t)w * 4]) = o;
    }
  }
}

extern "C" void kernel_launch(void* const* d_in, const int* in_sizes, int n_in,
                              void* d_out, int out_size, void* d_ws, size_t ws_size,
                              hipStream_t stream) {
  const float* x      = (const float*)d_in[0];
  const float* w_feat = (const float*)d_in[1];
  const float* b_feat = (const float*)d_in[2];
  const float* w_kern = (const float*)d_in[3];
  const float* b_kern = (const float*)d_in[4];
  const float* w_badp = (const float*)d_in[5];
  const float* b_badp = (const float*)d_in[6];
  const float* w1 = (const float*)d_in[7];
  const float* b1 = (const float*)d_in[8];
  const float* w2 = (const float*)d_in[9];
  const float* b2 = (const float*)d_in[10];
  const float* w3 = (const float*)d_in[11];
  const float* b3 = (const float*)d_in[12];

  char* ws = (char*)d_ws;
  ushort* feat     = (ushort*)(ws);
  ushort* h1       = (ushort*)(ws);
  ushort* kernbias = (ushort*)(ws + 117964800);
  ushort* h2       = (ushort*)(ws + 117964800);
  ushort* wp1      = (ushort*)(ws + 147456000);
  ushort* wp2      = (ushort*)(ws + 147660800);
  ushort* wp3      = (ushort*)(ws + 147734528);
  ushort* sp       = (ushort*)(ws + 150994944);
  ushort* Bt       = (ushort*)(ws + 180486144);
  float*  bias896  = (float*)(ws + 184614912);

  pack_kernel<<<(896 * 2304 + 896 + 255) / 256, 256, 0, stream>>>(
      w_kern, b_kern, w_badp, b_badp, Bt, bias896);
  feat_kernel<<<4608, 256, 0, stream>>>(x, w_feat, b_feat, feat);
  gemm_kernel<<<dim3(144, 7), 256, 0, stream>>>(feat, Bt, bias896, kernbias);
  apply_kernel<<<2304, 256, 0, stream>>>(x, kernbias, sp);
  pack2_kernel<<<598, 256, 0, stream>>>(w1, w2, w3, wp1, wp2, wp3);
  conv1_kernel<<<dim3(10, 90, 2), 512, 0, stream>>>(sp, wp1, b1, h1);
  conv2_kernel<<<dim3(10, 90, 2), 256, 0, stream>>>(h1, wp2, b2, h2);
  conv3_kernel<<<dim3(10, 180, 2), 256, 0, stream>>>(h2, wp3, b3, (float*)d_out);
}